// Round 1
// baseline (1048.337 us; speedup 1.0000x reference)
//
#include <hip/hip_runtime.h>
#include <hip/hip_bf16.h>
#include <cstdint>

// LISTA: Z = eta(X@We^T + Z@S^T), 16 unrolled steps. B=16384, n=256, m=1024.
// Strategy: convert inputs to bf16 once, then 17 m97-style bf16 GEMMs
// (128x128 tile, BK=64, global_load_lds w=16, XOR-swizzled LDS). Kernel
// boundaries provide the inter-step device-wide sync. Z ping-pongs in ws
// as bf16; Bmat kept fp32 for accuracy (re-added every step).

typedef __attribute__((ext_vector_type(8))) short short8;   // 8 x bf16 (4 VGPRs)
typedef __attribute__((ext_vector_type(4))) float floatx4;  // mfma acc

__device__ __forceinline__ void g2lds16(const void* g, void* lds) {
    __builtin_amdgcn_global_load_lds(
        (const __attribute__((address_space(1))) uint32_t*)(uintptr_t)g,
        (__attribute__((address_space(3))) uint32_t*)(uintptr_t)lds,
        16, 0, 0);
}

// A: M x K bf16 row-major (k contiguous).  W: N x K bf16 row-major (k contiguous)
// C[i,j] = sum_k A[i,k] * W[j,k]   (i.e. A @ W^T)
// FIRST: write Bmat_out = C (fp32), Zout = eta(C)
// middle: C += Bmat_in; Zout = eta(C) bf16
// LAST:  C += Bmat_in; Fout = eta(C) fp32
template<int KSTEPS, bool FIRST, bool LAST>
__global__ void __launch_bounds__(256, 3)
lista_gemm(const unsigned short* __restrict__ A,
           const unsigned short* __restrict__ W,
           const float* __restrict__ Bmat_in,
           float* __restrict__ Bmat_out,
           const float* __restrict__ theta,
           unsigned short* __restrict__ Zout,
           float* __restrict__ Fout)
{
    constexpr int K  = KSTEPS * 64;   // elements
    constexpr int N  = 1024;
    constexpr int KB = K * 2;         // row stride bytes

    __shared__ unsigned short Ash[128 * 64];  // 16 KB, swizzled chunk layout
    __shared__ unsigned short Bsh[128 * 64];  // 16 KB

    const int t    = threadIdx.x;       // 0..255
    const int bm   = blockIdx.x;        // 0..127
    const int bn   = blockIdx.y;        // 0..7
    const int wave = t >> 6;
    const int lane = t & 63;
    const int wm   = wave >> 1;         // 0..1
    const int wn   = wave & 1;          // 0..1

    floatx4 acc[4][4];
#pragma unroll
    for (int i = 0; i < 4; ++i)
#pragma unroll
        for (int j = 0; j < 4; ++j) acc[i][j] = (floatx4){0.f, 0.f, 0.f, 0.f};

    // staging: 128 rows x 8 chunks(16B) per tile; thread t, call c handles
    // linear chunk I = c*256 + t -> row r = I>>3, slot ch = I&7.
    // slot ch holds GLOBAL chunk g = ch ^ (r&7)  (bank-conflict swizzle).
    const int r0 = t >> 3;
    const int ch = t & 7;

    const char* Abase = (const char*)A + (size_t)(bm * 128) * KB;
    const char* Wbase = (const char*)W + (size_t)(bn * 128) * KB;

    for (int kt = 0; kt < KSTEPS; ++kt) {
        __syncthreads();  // all waves done reading LDS from previous iter
#pragma unroll
        for (int c = 0; c < 4; ++c) {
            const int r = r0 + c * 32;
            const int g = ch ^ (r & 7);
            const size_t goff = (size_t)r * KB + (size_t)kt * 128 + g * 16;
            const int loff = (c * 256 + t) * 16;
            g2lds16(Abase + goff, (char*)Ash + loff);
            g2lds16(Wbase + goff, (char*)Bsh + loff);
        }
        __syncthreads();  // waits vmcnt(0): staged data visible

#pragma unroll
        for (int kk = 0; kk < 2; ++kk) {
            short8 af[4], bf[4];
            const int q  = lane >> 4;        // k-quad 0..3
            const int rl = lane & 15;        // row-in-frag
            const int gq = kk * 4 + q;       // global chunk 0..7
#pragma unroll
            for (int mi = 0; mi < 4; ++mi) {
                const int R = wm * 64 + mi * 16 + rl;
                af[mi] = *(const short8*)((const char*)Ash + R * 128 + ((gq ^ (R & 7)) * 16));
            }
#pragma unroll
            for (int ni = 0; ni < 4; ++ni) {
                const int R = wn * 64 + ni * 16 + rl;
                bf[ni] = *(const short8*)((const char*)Bsh + R * 128 + ((gq ^ (R & 7)) * 16));
            }
#pragma unroll
            for (int mi = 0; mi < 4; ++mi)
#pragma unroll
                for (int ni = 0; ni < 4; ++ni)
                    acc[mi][ni] = __builtin_amdgcn_mfma_f32_16x16x32_bf16(
                        af[mi], bf[ni], acc[mi][ni], 0, 0, 0);
        }
    }

    // epilogue: C/D layout col = lane&15, row = (lane>>4)*4 + reg
    const int col_base = bn * 128 + wn * 64;
    const int row_base = bm * 128 + wm * 64;
#pragma unroll
    for (int ni = 0; ni < 4; ++ni) {
        const int col = col_base + ni * 16 + (lane & 15);
        const float th = theta[col];
#pragma unroll
        for (int mi = 0; mi < 4; ++mi) {
            const int row0 = row_base + mi * 16 + (lane >> 4) * 4;
#pragma unroll
            for (int v = 0; v < 4; ++v) {
                const size_t idx = (size_t)(row0 + v) * N + col;
                float c = acc[mi][ni][v];
                if constexpr (!FIRST) c += Bmat_in[idx];
                if constexpr (FIRST)  Bmat_out[idx] = c;
                const float a = fabsf(c) - th;
                const float z = a > 0.f ? (c > 0.f ? a : -a) : 0.f;
                if constexpr (LAST) {
                    Fout[idx] = z;
                } else {
                    __hip_bfloat16 hb = __float2bfloat16(z);
                    Zout[idx] = *(unsigned short*)&hb;
                }
            }
        }
    }
}

__global__ void __launch_bounds__(256)
cvt4(const float* __restrict__ s, unsigned short* __restrict__ d, int n4)
{
    const int i = blockIdx.x * blockDim.x + threadIdx.x;
    if (i < n4) {
        const float4 v = ((const float4*)s)[i];
        ushort4 o;
        __hip_bfloat16 b;
        b = __float2bfloat16(v.x); o.x = *(unsigned short*)&b;
        b = __float2bfloat16(v.y); o.y = *(unsigned short*)&b;
        b = __float2bfloat16(v.z); o.z = *(unsigned short*)&b;
        b = __float2bfloat16(v.w); o.w = *(unsigned short*)&b;
        ((ushort4*)d)[i] = o;
    }
}

extern "C" void kernel_launch(void* const* d_in, const int* in_sizes, int n_in,
                              void* d_out, int out_size, void* d_ws, size_t ws_size,
                              hipStream_t stream) {
    const float* X     = (const float*)d_in[0];  // 16384 x 256
    const float* We    = (const float*)d_in[1];  // 1024 x 256
    const float* S     = (const float*)d_in[2];  // 1024 x 1024
    const float* theta = (const float*)d_in[3];  // 1024
    float* out = (float*)d_out;                  // 16384 x 1024 fp32

    char* ws = (char*)d_ws;
    unsigned short* S_bf  = (unsigned short*)(ws);                        //  2 MB
    unsigned short* X_bf  = (unsigned short*)(ws + (size_t)(2)   * 1048576);  //  8 MB
    unsigned short* We_bf = (unsigned short*)(ws + (size_t)(10)  * 1048576);  // 0.5 MB
    float*          Bmat  = (float*)         (ws + (size_t)(11)  * 1048576);  // 64 MB
    unsigned short* Za    = (unsigned short*)(ws + (size_t)(75)  * 1048576);  // 32 MB
    unsigned short* Zb    = (unsigned short*)(ws + (size_t)(107) * 1048576);  // 32 MB  (total 139 MB)

    cvt4<<<dim3(1024), dim3(256), 0, stream>>>(S,  S_bf,  1024 * 1024 / 4);
    cvt4<<<dim3(4096), dim3(256), 0, stream>>>(X,  X_bf,  16384 * 256 / 4);
    cvt4<<<dim3(256),  dim3(256), 0, stream>>>(We, We_bf, 1024 * 256 / 4);

    const dim3 grid(128, 8), blk(256);

    // B = X @ We^T (K=256); Bmat fp32 + Z0 bf16
    lista_gemm<4, true, false><<<grid, blk, 0, stream>>>(
        X_bf, We_bf, nullptr, Bmat, theta, Za, nullptr);

    // steps 1..15: Z = eta(Bmat + Z @ S^T), ping-pong bf16
    unsigned short* zin = Za;
    unsigned short* zout = Zb;
    for (int tstep = 1; tstep <= 15; ++tstep) {
        lista_gemm<16, false, false><<<grid, blk, 0, stream>>>(
            zin, S_bf, Bmat, nullptr, theta, zout, nullptr);
        unsigned short* tmp = zin; zin = zout; zout = tmp;
    }
    // step 16: write fp32 output directly
    lista_gemm<16, false, true><<<grid, blk, 0, stream>>>(
        zin, S_bf, Bmat, nullptr, theta, nullptr, out);
}